// Round 9
// baseline (21917.595 us; speedup 1.0000x reference)
//
#include <hip/hip_runtime.h>

// Neural ODE RK4: weights live in LDS (transposed + padded), not registers —
// sidesteps the allocator behavior that kept 128 weights/lane in spill space
// for 4 straight rounds (VGPR stuck at 84-88, FETCH 1.24 GB).
// 256 blocks x 512 thr (8 waves): block owns 4 batch rows; wave (r2,hh) =
// row-pair {2r2,2r2+1} x hidden slice [64hh,64hh+64). Each weight ds_read
// amortized over 2 rows. W1T rows padded to 68 floats, W2T to 260: bank
// pattern 4(l+q)%32 -> uniform 8 words/bank, optimal b128 throughput.
// Per eval: 256 FMA/lane, 32 distinct b128 + 64 bcast b128, ONE barrier.

#define NB 1024
#define ND 64
#define NH 256
#define RPB 4               // batch rows per block
#define NBLK (NB / RPB)     // 256 blocks = 1/CU
#define NTHR 512            // 8 waves

#define W1T_LD 68
#define W2T_LD 260
#define W1T_OFF 0
#define W2T_OFF (W1T_OFF + NH * W1T_LD)     // 17408 floats
#define XP_OFF  (W2T_OFF + ND * W2T_LD)     // 34048 (16B-aligned: 136192 B)
#define AP_OFF  (XP_OFF + 8 * 2 * ND)       // 35072
#define PART_OFF (AP_OFF + 8 * 2 * ND)      // 36096
#define PART_SZ (4 * ND * 5)                // stride-5: conflict-free
#define LDS_FLOATS (PART_OFF + 2 * PART_SZ) // 38656 fl = 154624 B

__device__ __forceinline__ float fast_tanh(float x) {
    // tanh(x) = 1 - 2/(1+e^{2x})
    float e = __expf(2.0f * x);
    float r = __builtin_amdgcn_rcpf(e + 1.0f);
    return 1.0f - 2.0f * r;
}

// lgkmcnt-only barrier: no vmcnt drain (output stores keep flowing).
#define BLOCK_SYNC() do {                                        \
    asm volatile("s_waitcnt lgkmcnt(0)" ::: "memory");           \
    __builtin_amdgcn_s_barrier();                                \
    asm volatile("" ::: "memory");                               \
} while (0)

// One func eval for the wave's 2 rows. X0/X1,K0/K1: elem-per-lane (dim = l).
#define EVAL(X0, X1, K0, K1) do {                                 \
    lds[xp + l]      = (X0);                                      \
    lds[xp + ND + l] = (X1);                                      \
    float h0a = b1l, h1a = 0.0f, h0b = b1l, h1b = 0.0f;           \
    _Pragma("unroll")                                             \
    for (int q = 0; q < 16; ++q) {                                \
        float4 wv = *(const float4*)(lds + w1r + 4*q);            \
        float4 xa = *(const float4*)(lds + xp + 4*q);             \
        float4 xb = *(const float4*)(lds + xp + ND + 4*q);        \
        h0a = fmaf(wv.x, xa.x, h0a); h0b = fmaf(wv.x, xb.x, h0b); \
        h1a = fmaf(wv.y, xa.y, h1a); h1b = fmaf(wv.y, xb.y, h1b); \
        h0a = fmaf(wv.z, xa.z, h0a); h0b = fmaf(wv.z, xb.z, h0b); \
        h1a = fmaf(wv.w, xa.w, h1a); h1b = fmaf(wv.w, xb.w, h1b); \
    }                                                             \
    lds[ap + l]      = fast_tanh(h0a + h1a);                      \
    lds[ap + ND + l] = fast_tanh(h0b + h1b);                      \
    float p0a = 0.0f, p1a = 0.0f, p0b = 0.0f, p1b = 0.0f;         \
    _Pragma("unroll")                                             \
    for (int q = 0; q < 16; ++q) {                                \
        float4 wv = *(const float4*)(lds + w2r + 4*q);            \
        float4 va = *(const float4*)(lds + ap + 4*q);             \
        float4 vb = *(const float4*)(lds + ap + ND + 4*q);        \
        p0a = fmaf(wv.x, va.x, p0a); p0b = fmaf(wv.x, vb.x, p0b); \
        p1a = fmaf(wv.y, va.y, p1a); p1b = fmaf(wv.y, vb.y, p1b); \
        p0a = fmaf(wv.z, va.z, p0a); p0b = fmaf(wv.z, vb.z, p0b); \
        p1a = fmaf(wv.w, va.w, p1a); p1b = fmaf(wv.w, vb.w, p1b); \
    }                                                             \
    { int po = PART_OFF + pb * PART_SZ + l * 5 + hh;              \
      lds[po + (2*r2 + 0) * (ND*5)] = p0a + p1a;                  \
      lds[po + (2*r2 + 1) * (ND*5)] = p0b + p1b; }                \
    BLOCK_SYNC();                                                 \
    { int pr = PART_OFF + pb * PART_SZ + l * 5;                   \
      int ra = pr + (2*r2 + 0) * (ND*5);                          \
      int rb = pr + (2*r2 + 1) * (ND*5);                          \
      K0 = ((lds[ra] + lds[ra+1]) + (lds[ra+2] + lds[ra+3])) + b2l; \
      K1 = ((lds[rb] + lds[rb+1]) + (lds[rb+2] + lds[rb+3])) + b2l; } \
    pb ^= 1;  /* WAR separated by next eval's barrier */          \
} while (0)

__global__ __launch_bounds__(NTHR)
void node_rk4_kernel(const float* __restrict__ y0,
                     const float* __restrict__ t,
                     const float* __restrict__ W1,
                     const float* __restrict__ b1,
                     const float* __restrict__ W2,
                     const float* __restrict__ b2,
                     float* __restrict__ out,
                     int nsteps)
{
    extern __shared__ float lds[];
    const int tid = threadIdx.x;
    const int w   = tid >> 6;         // wave 0..7
    const int l   = tid & 63;         // lane
    const int r2  = w >> 2;           // row-pair within block
    const int hh  = w & 3;            // hidden slice
    const int j   = (hh << 6) + l;    // owned hidden unit

    // ---- one-time staging: W1^T and W2^T into padded LDS ----
    for (int idx = tid; idx < ND * NH; idx += NTHR) {    // W1 [64][256]
        int i = idx >> 8, jj = idx & (NH - 1);
        lds[W1T_OFF + jj * W1T_LD + i] = W1[idx];
    }
    for (int idx = tid; idx < NH * ND; idx += NTHR) {    // W2 [256][64]
        int jj = idx >> 6, d = idx & (ND - 1);
        lds[W2T_OFF + d * W2T_LD + jj] = W2[idx];
    }
    __syncthreads();

    const int w1r = W1T_OFF + j * W1T_LD;             // W1T row j
    const int w2r = W2T_OFF + l * W2T_LD + (hh << 6); // W2T row l, slice hh
    const int xp  = XP_OFF + w * 2 * ND;              // wave-private x bcast
    const int ap  = AP_OFF + w * 2 * ND;              // wave-private act bcast
    const float b1l = b1[j];
    const float b2l = b2[l];

    const int row0 = blockIdx.x * RPB + 2 * r2;
    float ya = y0[(row0 + 0) * ND + l];
    float yb = y0[(row0 + 1) * ND + l];
    if (hh == 0) {
        out[(row0 + 0) * ND + l] = ya;    // step-0 output = y0
        out[(row0 + 1) * ND + l] = yb;
    }

    int pb = 0;
    for (int s = 0; s < nsteps; ++s) {
        float dt  = t[s + 1] - t[s];      // func autonomous; only dt matters
        float dt2 = 0.5f * dt;
        float k1a, k1b, k2a, k2b, k3a, k3b, k4a, k4b;
        EVAL(ya, yb, k1a, k1b);
        EVAL(fmaf(dt2, k1a, ya), fmaf(dt2, k1b, yb), k2a, k2b);
        EVAL(fmaf(dt2, k2a, ya), fmaf(dt2, k2b, yb), k3a, k3b);
        EVAL(fmaf(dt,  k3a, ya), fmaf(dt,  k3b, yb), k4a, k4b);
        float c = dt * (1.0f / 6.0f);
        ya = fmaf(c, (k1a + k4a) + 2.0f * (k2a + k3a), ya);
        yb = fmaf(c, (k1b + k4b) + 2.0f * (k2b + k3b), yb);
        if (hh == 0) {                    // hh-waves redundant; store once
            size_t o = (size_t)(s + 1) * (NB * ND);
            out[o + (row0 + 0) * ND + l] = ya;
            out[o + (row0 + 1) * ND + l] = yb;
        }
    }
}

extern "C" void kernel_launch(void* const* d_in, const int* in_sizes, int n_in,
                              void* d_out, int out_size, void* d_ws, size_t ws_size,
                              hipStream_t stream) {
    const float* y0 = (const float*)d_in[0];
    const float* t  = (const float*)d_in[1];
    const float* W1 = (const float*)d_in[2];
    const float* b1 = (const float*)d_in[3];
    const float* W2 = (const float*)d_in[4];
    const float* b2 = (const float*)d_in[5];
    float* out = (float*)d_out;
    int nsteps = in_sizes[1] - 1;

    size_t ldsB = (size_t)LDS_FLOATS * sizeof(float);   // 154624 B < 160 KiB
    hipFuncSetAttribute(reinterpret_cast<const void*>(node_rk4_kernel),
                        hipFuncAttributeMaxDynamicSharedMemorySize, (int)ldsB);
    hipLaunchKernelGGL(node_rk4_kernel, dim3(NBLK), dim3(NTHR), ldsB, stream,
                       y0, t, W1, b1, W2, b2, out, nsteps);
}

// Round 10
// 9891.822 us; speedup vs baseline: 2.2157x; 2.2157x over previous
//
#include <hip/hip_runtime.h>

// Neural ODE RK4, fp32. Weights in LDS, PRE-PACKED in per-lane read order:
// every weight access is ds_read_b128 at (base + lane*16B) - the lane-
// contiguous fragment pattern (m134: ~12cy, conflict-free). r9's row-stride
// pattern (addr = row(lane)*68) was the T2 bad pattern -> 6.3e9 conflicts.
// 256 blocks (1/CU) x 256 thr (4 waves). Block owns 4 batch rows; wave w owns
// hidden slice [64w,64w+64) and processes ALL 4 rows (amortizes each weight
// read over 4 rows: weight LDS traffic 128KB/CU-eval = 1024cy ~= FMA wall).
// Exchange: stride-5 partials (conflict-free, r3-verified). 1 barrier/eval.

#define NB 1024
#define ND 64
#define NH 256
#define RPB 4
#define NBLK (NB / RPB)   // 256
#define NTHR 256          // 4 waves

// LDS float offsets
#define W1P_OFF 0                           // [4][16][64][4] = 16384 fl
#define W2P_OFF 16384                       // 16384 fl
#define XB_OFF  32768                       // [4 waves][4 rows][64] = 1024
#define AB_OFF  33792                       // 1024
#define PART_OFF 34816                      // [2][4 rows][64*5] = 2560
#define LDS_FLOATS (PART_OFF + 2 * RPB * ND * 5)   // 37376 fl = 149504 B

__device__ __forceinline__ float fast_tanh(float x) {
    float e = __expf(2.0f * x);
    float r = __builtin_amdgcn_rcpf(e + 1.0f);
    return 1.0f - 2.0f * r;
}

// lgkmcnt-only barrier: no vmcnt drain (output stores keep flowing).
#define BLOCK_SYNC() do {                                        \
    asm volatile("s_waitcnt lgkmcnt(0)" ::: "memory");           \
    __builtin_amdgcn_s_barrier();                                \
    asm volatile("" ::: "memory");                               \
} while (0)

// One eval of func for the block's 4 rows. XARR/KARR: float[4], elem-per-lane.
#define EVAL(XARR, KARR) do {                                              \
    _Pragma("unroll")                                                      \
    for (int r = 0; r < RPB; ++r) xbw[(r << 6) + l] = (XARR)[r];           \
    float h_[RPB];                                                         \
    _Pragma("unroll")                                                      \
    for (int r = 0; r < RPB; ++r) h_[r] = b1l;                             \
    _Pragma("unroll")                                                      \
    for (int q = 0; q < 16; ++q) {                                         \
        float4 wv = *(const float4*)(W1w + (q << 8) + (l << 2));           \
        _Pragma("unroll")                                                  \
        for (int r = 0; r < RPB; ++r) {                                    \
            float4 xv = ((const float4*)(xbw + (r << 6)))[q];              \
            h_[r] = fmaf(wv.x, xv.x, h_[r]);                               \
            h_[r] = fmaf(wv.y, xv.y, h_[r]);                               \
            h_[r] = fmaf(wv.z, xv.z, h_[r]);                               \
            h_[r] = fmaf(wv.w, xv.w, h_[r]);                               \
        }                                                                  \
    }                                                                      \
    _Pragma("unroll")                                                      \
    for (int r = 0; r < RPB; ++r) abw[(r << 6) + l] = fast_tanh(h_[r]);    \
    float p_[RPB] = {0.0f, 0.0f, 0.0f, 0.0f};                              \
    _Pragma("unroll")                                                      \
    for (int q = 0; q < 16; ++q) {                                         \
        float4 wv = *(const float4*)(W2w + (q << 8) + (l << 2));           \
        _Pragma("unroll")                                                  \
        for (int r = 0; r < RPB; ++r) {                                    \
            float4 av = ((const float4*)(abw + (r << 6)))[q];              \
            p_[r] = fmaf(wv.x, av.x, p_[r]);                               \
            p_[r] = fmaf(wv.y, av.y, p_[r]);                               \
            p_[r] = fmaf(wv.z, av.z, p_[r]);                               \
            p_[r] = fmaf(wv.w, av.w, p_[r]);                               \
        }                                                                  \
    }                                                                      \
    _Pragma("unroll")                                                      \
    for (int r = 0; r < RPB; ++r)                                          \
        lds[PART_OFF + pb * 1280 + r * 320 + l * 5 + w] = p_[r];           \
    BLOCK_SYNC();                                                          \
    _Pragma("unroll")                                                      \
    for (int r = 0; r < RPB; ++r) {                                        \
        int ra = PART_OFF + pb * 1280 + r * 320 + l * 5;                   \
        (KARR)[r] = ((lds[ra] + lds[ra+1]) + (lds[ra+2] + lds[ra+3])) + b2l; \
    }                                                                      \
    pb ^= 1;  /* WAR separated by next eval's barrier */                   \
} while (0)

__global__ __launch_bounds__(NTHR)
void node_rk4_kernel(const float* __restrict__ y0,
                     const float* __restrict__ t,
                     const float* __restrict__ W1,
                     const float* __restrict__ b1,
                     const float* __restrict__ W2,
                     const float* __restrict__ b2,
                     float* __restrict__ out,
                     int nsteps)
{
    extern __shared__ float lds[];
    const int tid = threadIdx.x;
    const int w   = tid >> 6;        // wave -> hidden slice
    const int l   = tid & 63;        // lane -> dim / hidden offset

    // ---- one-time staging, pre-packed in read order ----
    // W1P[ww][q][ll][c] = W1[4q+c][64ww+ll];  W2P[ww][q][ll][c] = W2[64ww+4q+c][ll]
    for (int idx = tid; idx < 16384; idx += NTHR) {
        int c = idx & 3, ll = (idx >> 2) & 63, q = (idx >> 8) & 15, ww = idx >> 12;
        lds[W1P_OFF + idx] = W1[(4 * q + c) * NH + (ww << 6) + ll];
        lds[W2P_OFF + idx] = W2[((ww << 6) + (q << 2) + c) * ND + ll];
    }
    __syncthreads();

    const float* W1w = lds + W1P_OFF + (w << 12);
    const float* W2w = lds + W2P_OFF + (w << 12);
    float* xbw = lds + XB_OFF + (w << 8);   // wave-private x bcast [4][64]
    float* abw = lds + AB_OFF + (w << 8);   // wave-private act bcast [4][64]

    const float b1l = b1[(w << 6) + l];
    const float b2l = b2[l];

    const int row0 = blockIdx.x * RPB;
    float yv[RPB];
    #pragma unroll
    for (int r = 0; r < RPB; ++r) yv[r] = y0[(row0 + r) * ND + l];
    if (w == 0) {
        #pragma unroll
        for (int r = 0; r < RPB; ++r) out[(row0 + r) * ND + l] = yv[r];
    }

    int pb = 0;
    for (int s = 0; s < nsteps; ++s) {
        float dt  = t[s + 1] - t[s];
        float dt2 = 0.5f * dt;
        float k1[RPB], k2[RPB], k3[RPB], k4[RPB], xc[RPB];
        EVAL(yv, k1);
        #pragma unroll
        for (int r = 0; r < RPB; ++r) xc[r] = fmaf(dt2, k1[r], yv[r]);
        EVAL(xc, k2);
        #pragma unroll
        for (int r = 0; r < RPB; ++r) xc[r] = fmaf(dt2, k2[r], yv[r]);
        EVAL(xc, k3);
        #pragma unroll
        for (int r = 0; r < RPB; ++r) xc[r] = fmaf(dt, k3[r], yv[r]);
        EVAL(xc, k4);
        float c6 = dt * (1.0f / 6.0f);
        #pragma unroll
        for (int r = 0; r < RPB; ++r)
            yv[r] = fmaf(c6, (k1[r] + k4[r]) + 2.0f * (k2[r] + k3[r]), yv[r]);
        if (w == 0) {
            size_t o = (size_t)(s + 1) * (NB * ND);
            #pragma unroll
            for (int r = 0; r < RPB; ++r) out[o + (row0 + r) * ND + l] = yv[r];
        }
    }
}

extern "C" void kernel_launch(void* const* d_in, const int* in_sizes, int n_in,
                              void* d_out, int out_size, void* d_ws, size_t ws_size,
                              hipStream_t stream) {
    const float* y0 = (const float*)d_in[0];
    const float* t  = (const float*)d_in[1];
    const float* W1 = (const float*)d_in[2];
    const float* b1 = (const float*)d_in[3];
    const float* W2 = (const float*)d_in[4];
    const float* b2 = (const float*)d_in[5];
    float* out = (float*)d_out;
    int nsteps = in_sizes[1] - 1;

    size_t ldsB = (size_t)LDS_FLOATS * sizeof(float);   // 149504 B < 160 KiB
    hipFuncSetAttribute(reinterpret_cast<const void*>(node_rk4_kernel),
                        hipFuncAttributeMaxDynamicSharedMemorySize, (int)ldsB);
    hipLaunchKernelGGL(node_rk4_kernel, dim3(NBLK), dim3(NTHR), ldsB, stream,
                       y0, t, W1, b1, W2, b2, out, nsteps);
}

// Round 12
// 6425.785 us; speedup vs baseline: 3.4109x; 1.5394x over previous
//
#include <hip/hip_runtime.h>

// Neural ODE RK4, fp32. Weights in LDS, pre-packed in per-lane read order
// (r10: conflict-free verified, SQ_LDS_BANK_CONFLICT = 0).
// r10 lesson: 1 wave/SIMD (12.2% occ) left 3900 cy/eval of unhidden LDS
// latency. r11: 512 thr = 8 waves = 4 hidden-slices x 2 row-groups ->
// 2 waves/SIMD. Same per-SIMD FMA issue (1024 cy/eval), weight traffic
// 256KB/CU-eval (~1000 cy) - balanced, with 2-way stall interleaving.
// 256 blocks (1/CU) own 4 batch rows each; wave (rp,hh) = rows {2rp,2rp+1}
// x hidden slice [64hh,64hh+64). Stride-5 partial exchange, 1 barrier/eval.

#define NB 1024
#define ND 64
#define NH 256
#define RPB 4
#define NBLK (NB / RPB)   // 256
#define NTHR 512          // 8 waves

// LDS float offsets
#define W1P_OFF 0                            // [4][16][64][4] = 16384 fl
#define W2P_OFF 16384                        // 16384 fl
#define XB_OFF  32768                        // [8 waves][2 rows][64] = 1024
#define AB_OFF  33792                        // 1024
#define PART_OFF 34816                       // [2][4 rows][64*5] = 2560
#define LDS_FLOATS (PART_OFF + 2 * RPB * ND * 5)   // 37376 fl = 149504 B

__device__ __forceinline__ float fast_tanh(float x) {
    float e = __expf(2.0f * x);
    float r = __builtin_amdgcn_rcpf(e + 1.0f);
    return 1.0f - 2.0f * r;
}

// lgkmcnt-only barrier: no vmcnt drain (output stores keep flowing).
#define BLOCK_SYNC() do {                                        \
    asm volatile("s_waitcnt lgkmcnt(0)" ::: "memory");           \
    __builtin_amdgcn_s_barrier();                                \
    asm volatile("" ::: "memory");                               \
} while (0)

// One func eval for the wave's 2 rows. X0/X1 in, K0/K1 out, elem-per-lane.
// 4 FMA chains (2 per row) cover 4cy FMA latency at 2cy issue.
#define EVAL(X0, X1, K0, K1) do {                                          \
    xbw[l] = (X0);                                                         \
    xbw[ND + l] = (X1);                                                    \
    float h0a = b1l, h1a = 0.0f, h0b = b1l, h1b = 0.0f;                    \
    _Pragma("unroll")                                                      \
    for (int q = 0; q < 16; ++q) {                                         \
        float4 wv = *(const float4*)(W1w + (q << 8) + (l << 2));           \
        float4 xa = ((const float4*)xbw)[q];                               \
        float4 xb = ((const float4*)(xbw + ND))[q];                        \
        h0a = fmaf(wv.x, xa.x, h0a); h1a = fmaf(wv.y, xa.y, h1a);          \
        h0b = fmaf(wv.x, xb.x, h0b); h1b = fmaf(wv.y, xb.y, h1b);          \
        h0a = fmaf(wv.z, xa.z, h0a); h1a = fmaf(wv.w, xa.w, h1a);          \
        h0b = fmaf(wv.z, xb.z, h0b); h1b = fmaf(wv.w, xb.w, h1b);          \
    }                                                                      \
    abw[l]      = fast_tanh(h0a + h1a);                                    \
    abw[ND + l] = fast_tanh(h0b + h1b);                                    \
    float p0a = 0.0f, p1a = 0.0f, p0b = 0.0f, p1b = 0.0f;                  \
    _Pragma("unroll")                                                      \
    for (int q = 0; q < 16; ++q) {                                         \
        float4 wv = *(const float4*)(W2w + (q << 8) + (l << 2));           \
        float4 va = ((const float4*)abw)[q];                               \
        float4 vb = ((const float4*)(abw + ND))[q];                        \
        p0a = fmaf(wv.x, va.x, p0a); p1a = fmaf(wv.y, va.y, p1a);          \
        p0b = fmaf(wv.x, vb.x, p0b); p1b = fmaf(wv.y, vb.y, p1b);          \
        p0a = fmaf(wv.z, va.z, p0a); p1a = fmaf(wv.w, va.w, p1a);          \
        p0b = fmaf(wv.z, vb.z, p0b); p1b = fmaf(wv.w, vb.w, p1b);          \
    }                                                                      \
    lds[pob + 0   + l * 5] = p0a + p1a;                                    \
    lds[pob + 320 + l * 5] = p0b + p1b;                                    \
    BLOCK_SYNC();                                                          \
    { int ra = prb + 0   + l * 5;                                          \
      int rb = prb + 320 + l * 5;                                          \
      (K0) = ((lds[ra] + lds[ra+1]) + (lds[ra+2] + lds[ra+3])) + b2l;      \
      (K1) = ((lds[rb] + lds[rb+1]) + (lds[rb+2] + lds[rb+3])) + b2l; }    \
    pob ^= 1280; prb ^= 1280;  /* WAR separated by next eval's barrier */  \
} while (0)

__global__ __launch_bounds__(NTHR)
void node_rk4_kernel(const float* __restrict__ y0,
                     const float* __restrict__ t,
                     const float* __restrict__ W1,
                     const float* __restrict__ b1,
                     const float* __restrict__ W2,
                     const float* __restrict__ b2,
                     float* __restrict__ out,
                     int nsteps)
{
    extern __shared__ float lds[];
    const int tid = threadIdx.x;
    const int w   = tid >> 6;        // wave 0..7
    const int l   = tid & 63;        // lane
    const int hh  = w & 3;           // hidden slice
    const int rp  = w >> 2;          // row-group (2 rows each)

    // ---- one-time staging, pre-packed in per-lane read order ----
    // W1P[ww][q][ll][c] = W1[4q+c][64ww+ll];  W2P[ww][q][ll][c] = W2[64ww+4q+c][ll]
    for (int idx = tid; idx < 16384; idx += NTHR) {
        int c = idx & 3, ll = (idx >> 2) & 63, q = (idx >> 8) & 15, ww = idx >> 12;
        lds[W1P_OFF + idx] = W1[(4 * q + c) * NH + (ww << 6) + ll];
        lds[W2P_OFF + idx] = W2[((ww << 6) + (q << 2) + c) * ND + ll];
    }
    __syncthreads();

    const float* W1w = lds + W1P_OFF + (hh << 12);
    const float* W2w = lds + W2P_OFF + (hh << 12);
    float* xbw = lds + XB_OFF + (w << 7);   // wave-private x bcast [2][64]
    float* abw = lds + AB_OFF + (w << 7);   // wave-private act bcast [2][64]

    const float b1l = b1[(hh << 6) + l];
    const float b2l = b2[l];

    // part base: [pb][row][l*5+hh]; row = 2*rp + {0,1}
    int pob = PART_OFF + (2 * rp) * 320 + hh;   // write base (+l*5)
    int prb = PART_OFF + (2 * rp) * 320;        // read base  (+l*5)

    const int row0 = blockIdx.x * RPB + 2 * rp;
    float ya = y0[(row0 + 0) * ND + l];
    float yb = y0[(row0 + 1) * ND + l];
    if (hh == 0) {
        out[(row0 + 0) * ND + l] = ya;
        out[(row0 + 1) * ND + l] = yb;
    }

    for (int s = 0; s < nsteps; ++s) {
        float dt  = t[s + 1] - t[s];
        float dt2 = 0.5f * dt;
        float k1a, k1b, k2a, k2b, k3a, k3b, k4a, k4b;
        EVAL(ya, yb, k1a, k1b);
        EVAL(fmaf(dt2, k1a, ya), fmaf(dt2, k1b, yb), k2a, k2b);
        EVAL(fmaf(dt2, k2a, ya), fmaf(dt2, k2b, yb), k3a, k3b);
        EVAL(fmaf(dt,  k3a, ya), fmaf(dt,  k3b, yb), k4a, k4b);
        float c6 = dt * (1.0f / 6.0f);
        ya = fmaf(c6, (k1a + k4a) + 2.0f * (k2a + k3a), ya);
        yb = fmaf(c6, (k1b + k4b) + 2.0f * (k2b + k3b), yb);
        if (hh == 0) {
            size_t o = (size_t)(s + 1) * (NB * ND);
            out[o + (row0 + 0) * ND + l] = ya;
            out[o + (row0 + 1) * ND + l] = yb;
        }
    }
}

extern "C" void kernel_launch(void* const* d_in, const int* in_sizes, int n_in,
                              void* d_out, int out_size, void* d_ws, size_t ws_size,
                              hipStream_t stream) {
    const float* y0 = (const float*)d_in[0];
    const float* t  = (const float*)d_in[1];
    const float* W1 = (const float*)d_in[2];
    const float* b1 = (const float*)d_in[3];
    const float* W2 = (const float*)d_in[4];
    const float* b2 = (const float*)d_in[5];
    float* out = (float*)d_out;
    int nsteps = in_sizes[1] - 1;

    size_t ldsB = (size_t)LDS_FLOATS * sizeof(float);   // 149504 B < 160 KiB
    hipFuncSetAttribute(reinterpret_cast<const void*>(node_rk4_kernel),
                        hipFuncAttributeMaxDynamicSharedMemorySize, (int)ldsB);
    hipLaunchKernelGGL(node_rk4_kernel, dim3(NBLK), dim3(NTHR), ldsB, stream,
                       y0, t, W1, b1, W2, b2, out, nsteps);
}